// Round 1
// baseline (315.791 us; speedup 1.0000x reference)
//
#include <hip/hip_runtime.h>
#include <hip/hip_bf16.h>

typedef unsigned short u16;
typedef unsigned int u32;
typedef short bf16x8 __attribute__((ext_vector_type(8)));
typedef float f32x4 __attribute__((ext_vector_type(4)));

__device__ __forceinline__ u16 f2bf(float f) {
    u32 u = __builtin_bit_cast(u32, f);
    u32 r = (u + 0x7FFFu + ((u >> 16) & 1u)) >> 16;
    return (u16)r;
}

// async global->LDS, 16B per lane (lds dest = wave-uniform base + lane*16)
__device__ __forceinline__ void lds16(const void* g, void* s) {
    __builtin_amdgcn_global_load_lds(
        (const __attribute__((address_space(1))) u32*)g,
        (__attribute__((address_space(3))) u32*)s, 16, 0, 0);
}

// ---------------- P1: decisions -> path, and x -> bf16 ----------------
// one wave per token: 30 dot products over H=1024, butterfly reduce,
// sigmoid, leaf products. Also writes x_bf16.
__global__ __launch_bounds__(256) void path_kernel(
    const float* __restrict__ x, const float* __restrict__ Wd,
    const float* __restrict__ bd, float* __restrict__ path,
    u16* __restrict__ xb, int M) {
    int lane = threadIdx.x & 63;
    int wid = threadIdx.x >> 6;
    int m = blockIdx.x * 4 + wid;
    if (m >= M) return;

    const float* xr = x + (size_t)m * 1024;
    float v[16];
#pragma unroll
    for (int i = 0; i < 16; ++i) v[i] = xr[lane + 64 * i];
#pragma unroll
    for (int i = 0; i < 16; ++i) xb[(size_t)m * 1024 + lane + 64 * i] = f2bf(v[i]);

    // nodes needed by this lane's leaf (static-indexed arrays only)
    int leaf = lane & 15;
    int nd[4], bit[4];
#pragma unroll
    for (int k = 0; k < 4; ++k) {
        nd[k] = (1 << k) - 1 + (leaf & ((1 << k) - 1));
        bit[k] = (leaf >> k) & 1;
    }
    float z[4] = {0.f, 0.f, 0.f, 0.f};

    const float2* Wd2 = (const float2*)Wd;  // [n][h] -> (k0,k1)
    for (int n = 0; n < 15; ++n) {
        float s0 = 0.f, s1 = 0.f;
#pragma unroll
        for (int i = 0; i < 16; ++i) {
            float2 w = Wd2[n * 1024 + lane + 64 * i];
            s0 += v[i] * w.x;
            s1 += v[i] * w.y;
        }
#pragma unroll
        for (int off = 32; off; off >>= 1) {
            s0 += __shfl_xor(s0, off, 64);
            s1 += __shfl_xor(s1, off, 64);
        }
#pragma unroll
        for (int k = 0; k < 4; ++k)
            if (nd[k] == n) z[k] = bit[k] ? s1 : s0;
    }
    float p = 1.f;
#pragma unroll
    for (int k = 0; k < 4; ++k) {
        float zz = z[k] + bd[nd[k] * 2 + bit[k]];
        p *= 1.f / (1.f + expf(-zz));
    }
    if (lane < 16) path[(size_t)m * 16 + leaf] = p;
}

// ---------------- P2: Wl (l,h,n) fp32 -> WlT (l,n,h) bf16 ----------------
__global__ __launch_bounds__(256) void wlt_kernel(
    const float* __restrict__ Wl, u16* __restrict__ wlt) {
    __shared__ float tile[64][65];
    int l = blockIdx.z, hb = blockIdx.y, nb = blockIdx.x;
    int t = threadIdx.x;
    int r = t >> 2, cq = (t & 3) << 4;

    const float* src = Wl + ((size_t)(l * 1024 + hb * 64 + r)) * 1024 + nb * 64 + cq;
#pragma unroll
    for (int j = 0; j < 4; ++j) {
        float4 w = ((const float4*)src)[j];
        tile[r][cq + 4 * j + 0] = w.x;
        tile[r][cq + 4 * j + 1] = w.y;
        tile[r][cq + 4 * j + 2] = w.z;
        tile[r][cq + 4 * j + 3] = w.w;
    }
    __syncthreads();
    union { u16 u[16]; uint4 q[2]; } pk;
#pragma unroll
    for (int j = 0; j < 16; ++j) pk.u[j] = f2bf(tile[cq + j][r]);
    u16* dst = wlt + ((size_t)(l * 1024 + nb * 64 + r)) * 1024 + hb * 64 + cq;
    ((uint4*)dst)[0] = pk.q[0];
    ((uint4*)dst)[1] = pk.q[1];
}

// ---------------- G: out[m,n] = sum_l path[m,l] * (x[m,:] @ Wl[l,:,n]) + path@bl
// BM=128 BN=128 BK=64, 4 waves, wave tile 64x64, dbuf LDS, leaf-scaled dual acc.
__global__ __launch_bounds__(256, 1) void tree_gemm(
    const u16* __restrict__ xb, const u16* __restrict__ wlt,
    const float* __restrict__ path, const float* __restrict__ bl,
    float* __restrict__ out, int M) {
    __shared__ __align__(16) u16 Asm[2][128 * 64];  // [row 0..127][k 0..63], 128B rows, XOR-swizzled
    __shared__ __align__(16) u16 Bsm[2][128 * 64];  // [n   0..127][k 0..63]
    __shared__ __align__(16) float psm[128 * 16];

    const int tid = threadIdx.x, lane = tid & 63, wid = tid >> 6;
    const int wm = wid >> 1, wn = wid & 1;
    const int m0 = blockIdx.y * 128, n0 = blockIdx.x * 128;

    // stage path tile (contiguous 8KB)
    {
        const float4* ps = (const float4*)(path + (size_t)m0 * 16);
#pragma unroll
        for (int i = 0; i < 2; ++i) ((float4*)psm)[tid + 256 * i] = ps[tid + 256 * i];
    }

    // staging: source-column pre-swizzle so linear gload_lds lands swizzled.
    // LDS byte L in tile: row r=L>>7, holds global col bytes (L&127)^((r&7)<<4).
    const int colb = (((lane & 7) ^ (lane >> 3)) << 4);
    const int rl = lane >> 3;  // r&7 == lane>>3 for every segment

#define STAGE(buf, step)                                                            \
    {                                                                               \
        int l_ = (step) >> 4;                                                       \
        int h2_ = ((step) & 15) << 7; /* h0*2 bytes */                              \
        _Pragma("unroll") for (int i_ = 0; i_ < 4; ++i_) {                          \
            int seg_ = wid * 4 + i_;                                                \
            int r_ = seg_ * 8 + rl;                                                 \
            lds16((const char*)xb + (size_t)(m0 + r_) * 2048 + h2_ + colb,          \
                  (char*)Asm[buf] + seg_ * 1024);                                   \
            lds16((const char*)wlt + (size_t)(l_ * 1024 + n0 + r_) * 2048 + h2_ + colb, \
                  (char*)Bsm[buf] + seg_ * 1024);                                   \
        }                                                                           \
    }

    f32x4 accF[4][4], accL[4][4];
#pragma unroll
    for (int a = 0; a < 4; ++a)
#pragma unroll
        for (int b = 0; b < 4; ++b) {
            accF[a][b] = (f32x4){0.f, 0.f, 0.f, 0.f};
            accL[a][b] = (f32x4){0.f, 0.f, 0.f, 0.f};
        }

    STAGE(0, 0);
    __syncthreads();

    int cur = 0;
    for (int l = 0; l < 16; ++l) {
#pragma unroll 1
        for (int s = 0; s < 16; ++s) {
            int step = l * 16 + s;
            if (step + 1 < 256) STAGE(cur ^ 1, step + 1);

            bf16x8 af[4][2], bfr[4][2];
#pragma unroll
            for (int kf = 0; kf < 2; ++kf) {
                int c2 = kf * 64 + ((lane >> 4) << 4);
#pragma unroll
                for (int mf = 0; mf < 4; ++mf) {
                    int rr = wm * 64 + mf * 16 + (lane & 15);
                    int off = rr * 128 + (c2 ^ ((lane & 7) << 4));
                    af[mf][kf] = *(const bf16x8*)((const char*)Asm[cur] + off);
                }
#pragma unroll
                for (int nf = 0; nf < 4; ++nf) {
                    int rr = wn * 64 + nf * 16 + (lane & 15);
                    int off = rr * 128 + (c2 ^ ((lane & 7) << 4));
                    bfr[nf][kf] = *(const bf16x8*)((const char*)Bsm[cur] + off);
                }
            }
#pragma unroll
            for (int mf = 0; mf < 4; ++mf)
#pragma unroll
                for (int nf = 0; nf < 4; ++nf) {
                    accL[mf][nf] = __builtin_amdgcn_mfma_f32_16x16x32_bf16(
                        af[mf][0], bfr[nf][0], accL[mf][nf], 0, 0, 0);
                    accL[mf][nf] = __builtin_amdgcn_mfma_f32_16x16x32_bf16(
                        af[mf][1], bfr[nf][1], accL[mf][nf], 0, 0, 0);
                }
            __syncthreads();
            cur ^= 1;
        }
        // leaf boundary: accF += path[row, l] * accL ; accL = 0
#pragma unroll
        for (int mf = 0; mf < 4; ++mf)
#pragma unroll
            for (int jj = 0; jj < 4; ++jj) {
                float p = psm[(wm * 64 + mf * 16 + ((lane >> 4) << 2) + jj) * 16 + l];
#pragma unroll
                for (int nf = 0; nf < 4; ++nf) {
                    accF[mf][nf][jj] += p * accL[mf][nf][jj];
                    accL[mf][nf][jj] = 0.f;
                }
            }
    }

    // epilogue: out = accF + path @ bl
    float blr[4][16];
#pragma unroll
    for (int nf = 0; nf < 4; ++nf) {
        int col = n0 + wn * 64 + nf * 16 + (lane & 15);
#pragma unroll
        for (int l = 0; l < 16; ++l) blr[nf][l] = bl[l * 1024 + col];
    }
#pragma unroll
    for (int mf = 0; mf < 4; ++mf)
#pragma unroll
        for (int jj = 0; jj < 4; ++jj) {
            int rowl = wm * 64 + mf * 16 + ((lane >> 4) << 2) + jj;
            float pv[16];
#pragma unroll
            for (int l = 0; l < 16; ++l) pv[l] = psm[rowl * 16 + l];
#pragma unroll
            for (int nf = 0; nf < 4; ++nf) {
                float b = 0.f;
#pragma unroll
                for (int l = 0; l < 16; ++l) b += pv[l] * blr[nf][l];
                int col = n0 + wn * 64 + nf * 16 + (lane & 15);
                out[(size_t)(m0 + rowl) * 1024 + col] = accF[mf][nf][jj] + b;
            }
        }
#undef STAGE
}

extern "C" void kernel_launch(void* const* d_in, const int* in_sizes, int n_in,
                              void* d_out, int out_size, void* d_ws, size_t ws_size,
                              hipStream_t stream) {
    const float* x  = (const float*)d_in[0];   // (B,S,H)
    const float* Wd = (const float*)d_in[1];   // (15,H,2)
    const float* bd = (const float*)d_in[2];   // (15,2)
    const float* Wl = (const float*)d_in[3];   // (16,H,H)
    const float* bl = (const float*)d_in[4];   // (16,H)
    float* out = (float*)d_out;

    const int H = 1024;
    const int M = in_sizes[0] / H;  // B*S = 4096

    // workspace layout: path (M*16 f32) | x_bf16 (M*1024) | WlT (16*1024*1024 bf16)
    char* ws = (char*)d_ws;
    float* path = (float*)ws;
    u16* xb = (u16*)(ws + (size_t)M * 16 * 4);
    u16* wlt = (u16*)(ws + (size_t)M * 16 * 4 + (size_t)M * 1024 * 2);
    // needs ~40.3 MB of ws

    path_kernel<<<M / 4, 256, 0, stream>>>(x, Wd, bd, path, xb, M);
    wlt_kernel<<<dim3(16, 16, 16), 256, 0, stream>>>(Wl, wlt);
    tree_gemm<<<dim3(8, M / 128), 256, 0, stream>>>(xb, wlt, path, bl, out, M);
}